// Round 9
// baseline (156.894 us; speedup 1.0000x reference)
//
#include <hip/hip_runtime.h>

#define T_LEN 1024
#define NH 8
#define DH 64
#define CCH 512
#define LOG2E 1.44269504088896340736f

typedef _Float16 f16;
typedef _Float16 f16x8 __attribute__((ext_vector_type(8)));
typedef _Float16 f16x4 __attribute__((ext_vector_type(4)));
typedef float f32x4 __attribute__((ext_vector_type(4)));

// async global->LDS DMA, 16B per lane. LDS dest must equal wave-uniform base + lane*16.
__device__ __forceinline__ void dma16(const void* g, void* l)
{
    __builtin_amdgcn_global_load_lds((const __attribute__((address_space(1))) void*)g,
                                     (__attribute__((address_space(3))) void*)l, 16, 0, 0);
}

// ---------------------------------------------------------------------------
// prep: fused [transpose+cvt x -> xT fp16 [b*t][c]] and [W fp32 -> fp16].
// grid(16, 8, 3B + 8), block 256. (unchanged)
// ---------------------------------------------------------------------------
__global__ __launch_bounds__(256)
void prep_kernel(const float* __restrict__ x0, const float* __restrict__ x1,
                 const float* __restrict__ x2, const float* __restrict__ W0,
                 const float* __restrict__ W1, const float* __restrict__ W2,
                 const float* __restrict__ W3, f16* __restrict__ o0,
                 f16* __restrict__ o1, f16* __restrict__ o2, f16* __restrict__ w0,
                 f16* __restrict__ w1, f16* __restrict__ w2, f16* __restrict__ w3,
                 int B)
{
    const int z = blockIdx.z;
    if (z < 3 * B) {
        const int t0 = blockIdx.x * 64, c0 = blockIdx.y * 64;
        const int which = z / B, b = z % B;
        const float* x = (which == 0) ? x0 : (which == 1) ? x1 : x2;
        f16* o = (which == 0) ? o0 : (which == 1) ? o1 : o2;

        __shared__ float L[64 * 68];
        const int cl = threadIdx.x & 63, g = threadIdx.x >> 6;
        const float* src = x + ((size_t)(b * CCH + c0 + cl)) * T_LEN + t0 + g * 16;
        #pragma unroll
        for (int j = 0; j < 4; ++j)
            *(float4*)&L[cl * 68 + g * 16 + 4 * j] = *(const float4*)&src[4 * j];
        __syncthreads();
        const int tl = threadIdx.x & 63, cg = (threadIdx.x >> 6) * 16;
        f16 h[16];
        #pragma unroll
        for (int j = 0; j < 16; ++j) h[j] = (f16)L[(cg + j) * 68 + tl];
        f16* dst = o + ((size_t)(b * T_LEN + t0 + tl)) * CCH + c0 + cg;
        *(f16x8*)&dst[0] = *(f16x8*)&h[0];
        *(f16x8*)&dst[8] = *(f16x8*)&h[8];
    } else {
        const int slice = z - 3 * B;
        size_t i = ((size_t)(slice * 128 + blockIdx.y * 16 + blockIdx.x) * 256 + threadIdx.x) * 4;
        const int wi = (int)(i >> 18);
        const size_t off = i & 262143;
        const float* src = (wi == 0) ? W0 : (wi == 1) ? W1 : (wi == 2) ? W2 : W3;
        f16* dst = (wi == 0) ? w0 : (wi == 1) ? w1 : (wi == 2) ? w2 : w3;
        float4 v4 = *(const float4*)&src[off];
        f16x4 h = {(f16)v4.x, (f16)v4.y, (f16)v4.z, (f16)v4.w};
        *(f16x4*)&dst[off] = h;
    }
}

// ---------------------------------------------------------------------------
// Fused q/k/v projections (unchanged from R8): X A-frags via register dbuf,
// W via DMA-staged dbuf LDS. 128(t)x64(o), BK=64. grid(B*8, 8, 3), block 256.
// ---------------------------------------------------------------------------
__global__ __launch_bounds__(256)
void proj_qkv(const f16* __restrict__ xq, const f16* __restrict__ xk,
              const f16* __restrict__ xv, const f16* __restrict__ wq,
              const f16* __restrict__ wk, const f16* __restrict__ wv,
              const float* __restrict__ bq, const float* __restrict__ bk,
              const float* __restrict__ bv, f16* __restrict__ qo,
              f16* __restrict__ ko, f16* __restrict__ vo)
{
    const int which = blockIdx.z;
    const f16* X = (which == 0) ? xq : (which == 1) ? xk : xv;
    const f16* W = (which == 0) ? wq : (which == 1) ? wk : wv;
    const float* bias = (which == 0) ? bq : (which == 1) ? bk : bv;
    const float scale = (which == 0) ? 0.125f * LOG2E : 1.0f;

    const int r0 = blockIdx.x * 128;
    const int o0 = blockIdx.y * 64;
    const int tid = threadIdx.x;
    const int w = tid >> 6, lane = tid & 63;
    const int quad = lane >> 4, l15 = lane & 15;

    __shared__ __align__(16) f16 Ws[2][4096];

    const int srow = tid >> 3;
    const int scol = ((tid & 7) ^ (srow & 7)) << 3;
    const f16* Wg = W + (size_t)(o0 + srow) * CCH + scol;

    dma16(Wg, &Ws[0][(size_t)tid * 8]);
    dma16(Wg + (size_t)32 * CCH, &Ws[0][((size_t)tid + 256) * 8]);

    const f16* xp = X + (size_t)(r0 + 32 * w + l15) * CCH + quad * 8;
    f16x8 xf[2][2];
    #pragma unroll
    for (int ks = 0; ks < 2; ++ks)
        #pragma unroll
        for (int im = 0; im < 2; ++im)
            xf[ks][im] = *(const f16x8*)&xp[(size_t)(16 * im) * CCH + ks * 32];

    f32x4 acc[8] = {};

    for (int kc = 0; kc < 8; ++kc) {
        __syncthreads();
        if (kc < 7) {
            const int bf = (kc + 1) & 1, c1 = (kc + 1) * 64;
            dma16(Wg + c1, &Ws[bf][(size_t)tid * 8]);
            dma16(Wg + c1 + (size_t)32 * CCH, &Ws[bf][((size_t)tid + 256) * 8]);
        }
        const int nk = ((kc + 1) & 7) * 64;
        f16x8 xn[2][2];
        #pragma unroll
        for (int ks = 0; ks < 2; ++ks)
            #pragma unroll
            for (int im = 0; im < 2; ++im)
                xn[ks][im] = *(const f16x8*)&xp[(size_t)(16 * im) * CCH + nk + ks * 32];

        const int cb = kc & 1;
        #pragma unroll
        for (int ks = 0; ks < 2; ++ks) {
            const int sl = ((ks * 4 + quad) ^ (l15 & 7)) << 3;
            f16x8 wf[4];
            #pragma unroll
            for (int cm = 0; cm < 4; ++cm)
                wf[cm] = *(const f16x8*)&Ws[cb][(16 * cm + l15) * 64 + sl];
            if (which < 2) {
                #pragma unroll
                for (int im = 0; im < 2; ++im)
                    #pragma unroll
                    for (int cm = 0; cm < 4; ++cm)
                        acc[im * 4 + cm] = __builtin_amdgcn_mfma_f32_16x16x32_f16(
                            xf[ks][im], wf[cm], acc[im * 4 + cm], 0, 0, 0);
            } else {
                #pragma unroll
                for (int cm = 0; cm < 4; ++cm)
                    #pragma unroll
                    for (int in = 0; in < 2; ++in)
                        acc[cm * 2 + in] = __builtin_amdgcn_mfma_f32_16x16x32_f16(
                            wf[cm], xf[ks][in], acc[cm * 2 + in], 0, 0, 0);
            }
        }
        #pragma unroll
        for (int ks = 0; ks < 2; ++ks)
            #pragma unroll
            for (int im = 0; im < 2; ++im)
                xf[ks][im] = xn[ks][im];
    }

    if (which < 2) {
        f16* out = (which == 0) ? qo : ko;
        float bl[4];
        #pragma unroll
        for (int cm = 0; cm < 4; ++cm) bl[cm] = bias[o0 + 16 * cm + l15];
        #pragma unroll
        for (int im = 0; im < 2; ++im)
            #pragma unroll
            for (int r = 0; r < 4; ++r) {
                size_t row = (size_t)(r0 + 32 * w + 16 * im + 4 * quad + r) * CCH;
                #pragma unroll
                for (int cm = 0; cm < 4; ++cm)
                    out[row + o0 + 16 * cm + l15] =
                        (f16)((acc[im * 4 + cm][r] + bl[cm]) * scale);
            }
    } else {
        const int bb = r0 >> 10, tb = r0 & 1023;
        #pragma unroll
        for (int cm = 0; cm < 4; ++cm) {
            float4 bv4 = *(const float4*)&bias[o0 + 16 * cm + 4 * quad];
            float bl[4] = {bv4.x, bv4.y, bv4.z, bv4.w};
            #pragma unroll
            for (int r = 0; r < 4; ++r) {
                size_t row = ((size_t)(bb * CCH + o0 + 16 * cm + 4 * quad + r)) * T_LEN;
                #pragma unroll
                for (int in = 0; in < 2; ++in)
                    vo[row + tb + 32 * w + 16 * in + l15] =
                        (f16)(acc[cm * 2 + in][r] + bl[r]);
            }
        }
    }
}

// ---------------------------------------------------------------------------
// MFMA flash attention v7: 128 Q-rows per block, 512 threads (8 waves),
// grid(8, NH, B) = 256 blocks. Halves per-CU barrier events and K/V
// streaming; 16 waves/CU (69 KB LDS -> 2 blocks/CU). One barrier per K-iter,
// cross-barrier DMA prefetch, wave-private Ps (no P barrier).
// Writes final normalized ctx f16 [b*t][c].
// ---------------------------------------------------------------------------
__global__ __launch_bounds__(512)
void attn_mfma(const f16* __restrict__ q, const f16* __restrict__ kk,
               const f16* __restrict__ v, const float* __restrict__ ekg,
               const float* __restrict__ evg, f16* __restrict__ ctx)
{
    const int t0 = blockIdx.x * 128, h = blockIdx.y, b = blockIdx.z;
    const int tid = threadIdx.x;
    const int w = tid >> 6, lane = tid & 63;
    const int quad = lane >> 4, l15 = lane & 15;

    __shared__ __align__(16) f16 Qs[8192], Ps[8192];
    __shared__ __align__(16) f16 Ks[2][4096], Vs[2][4096];
    __shared__ float eks[576], evs[576];
    __shared__ float ls[128];

    const int srow = tid >> 3;                       // 0..63
    const int scol = ((tid & 7) ^ (srow & 7)) << 3;

    for (int i = tid; i < 576; i += 512) {
        eks[i] = ekg[h * 576 + i];
        evs[i] = evg[h * 576 + i];
    }

    const f16* gk = kk + ((size_t)(b * T_LEN + srow)) * CCH + h * DH + scol;
    const f16* gv = v + ((size_t)(b * CCH + h * DH + srow)) * T_LEN + scol;

    // prologue: Q (128 rows, 2 dma/thread) + tile 0 (1 dma/thread each)
    dma16(q + ((size_t)(b * T_LEN + t0 + srow)) * CCH + h * DH + scol, &Qs[(size_t)tid * 8]);
    dma16(q + ((size_t)(b * T_LEN + t0 + 64 + srow)) * CCH + h * DH + scol, &Qs[((size_t)tid + 512) * 8]);
    dma16(gk, &Ks[0][(size_t)tid * 8]);
    dma16(gv, &Vs[0][(size_t)tid * 8]);
    __syncthreads();

    f16x8 qf[2];
    #pragma unroll
    for (int ks = 0; ks < 2; ++ks)
        qf[ks] = *(const f16x8*)&Qs[(16 * w + l15) * 64 + (((ks * 4 + quad) ^ (l15 & 7)) << 3)];

    const int myt = 16 * w + l15;   // this lane's t-column, 0..127
    float Ssum = 0.f;
    f32x4 O[4] = {};

    const bool corner_hi = (blockIdx.x == 0);
    const bool corner_lo = (blockIdx.x == 7);

    for (int it = 0; it < 16; ++it) {
        const int kb = it, cb = it & 1;
        if (it) __syncthreads();   // single barrier: drains DMA(tile it), swaps buffers

        // ----- prefetch DMA for tile it+1 (flies across the whole iteration)
        if (it < 15) {
            const int nb = cb ^ 1;
            dma16(gk + (size_t)((it + 1) * 64) * CCH, &Ks[nb][(size_t)tid * 8]);
            dma16(gv + (it + 1) * 64, &Vs[nb][(size_t)tid * 8]);
        }

        // ----- S^T = K Q^T : D[s][t], lane col t = myt, rows s = 16ct+4quad+r
        f32x4 S[4] = {};
        #pragma unroll
        for (int ks = 0; ks < 2; ++ks) {
            #pragma unroll
            for (int ct = 0; ct < 4; ++ct) {
                f16x8 a = *(const f16x8*)&Ks[cb][(16 * ct + l15) * 64 + (((ks * 4 + quad) ^ (l15 & 7)) << 3)];
                S[ct] = __builtin_amdgcn_mfma_f32_16x16x32_f16(a, qf[ks], S[ct], 0, 0, 0);
            }
        }

        // ----- corner relative-K bias (rare) -----
        if ((corner_hi && kb == 15) || (corner_lo && kb == 0)) {
            const int s0g = kb * 64;
            #pragma unroll
            for (int ct = 0; ct < 4; ++ct)
                #pragma unroll
                for (int r = 0; r < 4; ++r) {
                    int t_g = t0 + myt;
                    int s_g = s0g + 16 * ct + 4 * quad + r;
                    int df = s_g - t_g;
                    if (df >= 1019 && df <= 1023) {
                        const float* ekp = &eks[(df - 1019) * 64];
                        float sacc = 0.f;
                        for (int d = 0; d < 64; ++d)
                            sacc += (float)Qs[myt * 64 + (((d >> 3) ^ (myt & 7)) << 3) + (d & 7)] * ekp[d];
                        S[ct][r] += sacc;
                    } else if (df >= -1023 && df <= -1021) {
                        const float* ekp = &eks[(1029 + df) * 64];
                        const int t2 = myt - 1;   // trigger needs t_g>=1021 -> myt>=125
                        float sacc = 0.f;
                        for (int d = 0; d < 64; ++d)
                            sacc += (float)Qs[t2 * 64 + (((d >> 3) ^ (t2 & 7)) << 3) + (d & 7)] * ekp[d];
                        S[ct][r] += sacc;
                    }
                }
        }

        // ----- no-max softmax: P = exp2(S); store Ps (wave-private rows) -----
        #pragma unroll
        for (int ct = 0; ct < 4; ++ct) {
            f16x4 pk_;
            #pragma unroll
            for (int r = 0; r < 4; ++r) {
                float p = exp2f(S[ct][r]);
                Ssum += p;
                pk_[r] = (f16)p;
            }
            int colh = (((2 * ct + (quad >> 1)) ^ (myt & 7)) << 3) + (quad & 1) * 4;
            *(f16x4*)&Ps[myt * 64 + colh] = pk_;
        }
        // no barrier: Ps rows 16w..16w+15 written & read by wave w only.

        // ----- O += P V : D[t][d], rows t = 16w+4quad+r, cols d = 16ct+l15
        #pragma unroll
        for (int ks = 0; ks < 2; ++ks) {
            f16x8 a = *(const f16x8*)&Ps[(16 * w + l15) * 64 + (((ks * 4 + quad) ^ (l15 & 7)) << 3)];
            #pragma unroll
            for (int ct = 0; ct < 4; ++ct) {
                f16x8 bf = *(const f16x8*)&Vs[cb][(16 * ct + l15) * 64 + (((ks * 4 + quad) ^ (l15 & 7)) << 3)];
                O[ct] = __builtin_amdgcn_mfma_f32_16x16x32_f16(a, bf, O[ct], 0, 0, 0);
            }
        }

        // ----- windowed relative-V (reads own wave's Ps rows) -----
        const int s0g = kb * 64;
        if (s0g <= t0 + 131 && s0g + 63 >= t0 - 4) {
            #pragma unroll
            for (int r = 0; r < 4; ++r) {
                int t_loc = 16 * w + 4 * quad + r;
                int t_g = t0 + t_loc;
                int slo = max(s0g, t_g - 4), shi = min(s0g + 63, t_g + 4);
                for (int s = slo; s <= shi; ++s) {
                    int sl = s - s0g;
                    float p = (float)Ps[t_loc * 64 + (((sl >> 3) ^ (t_loc & 7)) << 3) + (sl & 7)];
                    const float* evp = &evs[(s - t_g + 4) * 64];
                    #pragma unroll
                    for (int ct = 0; ct < 4; ++ct)
                        O[ct][r] += p * evp[16 * ct + l15];
                }
            }
        }
    }

    // full row-sum -> normalize in-kernel (ls rows are wave-private)
    Ssum += __shfl_xor(Ssum, 16);
    Ssum += __shfl_xor(Ssum, 32);
    if (quad == 0) ls[myt] = 1.0f / Ssum;
    __syncthreads();

    #pragma unroll
    for (int r = 0; r < 4; ++r) {
        const int t_loc = 16 * w + 4 * quad + r;
        const float rl = ls[t_loc];
        size_t rowo = ((size_t)(b * T_LEN + t0 + t_loc)) * CCH + h * DH;
        #pragma unroll
        for (int ct = 0; ct < 4; ++ct)
            ctx[rowo + 16 * ct + l15] = (f16)(O[ct][r] * rl);
    }
}

// ---------------------------------------------------------------------------
// Output projection (unchanged from R8): ctx B-frags via register dbuf,
// Wo via DMA-staged dbuf LDS. 64(o)x64(t), BK=64. grid(B*16, 8).
// fp32 out [b][o][t].
// ---------------------------------------------------------------------------
__global__ __launch_bounds__(256)
void proj_out(const f16* __restrict__ ctx, const f16* __restrict__ Wo,
              const float* __restrict__ bo, float* __restrict__ out)
{
    const int r0 = blockIdx.x * 64;
    const int o0 = blockIdx.y * 64;
    const int tid = threadIdx.x;
    const int w = tid >> 6, lane = tid & 63;
    const int quad = lane >> 4, l15 = lane & 15;

    __shared__ __align__(16) f16 Ws[2][4096];

    const int srow = tid >> 3;
    const int scol = ((tid & 7) ^ (srow & 7)) << 3;
    const f16* Wg = Wo + (size_t)(o0 + srow) * CCH + scol;

    dma16(Wg, &Ws[0][(size_t)tid * 8]);
    dma16(Wg + (size_t)32 * CCH, &Ws[0][((size_t)tid + 256) * 8]);

    const f16* cp = ctx + (size_t)(r0 + 16 * w + l15) * CCH + quad * 8;
    f16x8 cf[2];
    #pragma unroll
    for (int ks = 0; ks < 2; ++ks)
        cf[ks] = *(const f16x8*)&cp[ks * 32];

    f32x4 acc[4] = {};

    for (int kc = 0; kc < 8; ++kc) {
        __syncthreads();
        if (kc < 7) {
            const int bf = (kc + 1) & 1, c1 = (kc + 1) * 64;
            dma16(Wg + c1, &Ws[bf][(size_t)tid * 8]);
            dma16(Wg + c1 + (size_t)32 * CCH, &Ws[bf][((size_t)tid + 256) * 8]);
        }
        const int nk = ((kc + 1) & 7) * 64;
        f16x8 cn[2];
        #pragma unroll
        for (int ks = 0; ks < 2; ++ks)
            cn[ks] = *(const f16x8*)&cp[nk + ks * 32];

        const int cb = kc & 1;
        #pragma unroll
        for (int ks = 0; ks < 2; ++ks) {
            const int sl = ((ks * 4 + quad) ^ (l15 & 7)) << 3;
            #pragma unroll
            for (int cm = 0; cm < 4; ++cm) {
                f16x8 wf = *(const f16x8*)&Ws[cb][(16 * cm + l15) * 64 + sl];
                acc[cm] = __builtin_amdgcn_mfma_f32_16x16x32_f16(wf, cf[ks], acc[cm], 0, 0, 0);
            }
        }
        cf[0] = cn[0];
        cf[1] = cn[1];
    }

    const int bb = r0 >> 10, tb = r0 & 1023;
    #pragma unroll
    for (int cm = 0; cm < 4; ++cm) {
        float4 bv4 = *(const float4*)&bo[o0 + 16 * cm + 4 * quad];
        float bl[4] = {bv4.x, bv4.y, bv4.z, bv4.w};
        #pragma unroll
        for (int r = 0; r < 4; ++r) {
            size_t row = ((size_t)(bb * CCH + o0 + 16 * cm + 4 * quad + r)) * T_LEN;
            out[row + tb + 16 * w + l15] = acc[cm][r] + bl[r];
        }
    }
}

// ---------------------------------------------------------------------------
extern "C" void kernel_launch(void* const* d_in, const int* in_sizes, int n_in,
                              void* d_out, int out_size, void* d_ws, size_t ws_size,
                              hipStream_t stream)
{
    const float* x_q = (const float*)d_in[0];
    const float* x_k = (const float*)d_in[1];
    const float* x_v = (const float*)d_in[2];
    const float* Wq  = (const float*)d_in[3];
    const float* bq  = (const float*)d_in[4];
    const float* Wk  = (const float*)d_in[5];
    const float* bk  = (const float*)d_in[6];
    const float* Wv  = (const float*)d_in[7];
    const float* bv  = (const float*)d_in[8];
    const float* Wo  = (const float*)d_in[9];
    const float* bo  = (const float*)d_in[10];
    const float* erk = (const float*)d_in[11];
    const float* erv = (const float*)d_in[12];

    const int B = in_sizes[0] / (CCH * T_LEN);
    const size_t te = (size_t)B * CCH * T_LEN;
    const size_t we = (size_t)CCH * CCH;

    f16* p = (f16*)d_ws;
    f16* xTq = p; p += te;
    f16* xTk = p; p += te;
    f16* xTv = p; p += te;
    f16* wqh = p; p += we;
    f16* wkh = p; p += we;
    f16* wvh = p; p += we;
    f16* woh = p; p += we;
    f16* qh  = p; p += te;
    f16* kh  = p; p += te;
    f16* vh  = p; p += te;
    f16* ch  = p; p += te;

    dim3 blk(256);
    prep_kernel<<<dim3(16, 8, 3 * B + 8), blk, 0, stream>>>(
        x_q, x_k, x_v, Wq, Wk, Wv, Wo, xTq, xTk, xTv, wqh, wkh, wvh, woh, B);
    proj_qkv<<<dim3(B * 8, 8, 3), blk, 0, stream>>>(
        xTq, xTk, xTv, wqh, wkh, wvh, bq, bk, bv, qh, kh, vh);
    attn_mfma<<<dim3(T_LEN / 128, NH, B), dim3(512), 0, stream>>>(
        qh, kh, vh, erk, erv, ch);
    proj_out<<<dim3(B * 16, 8), blk, 0, stream>>>(
        ch, woh, bo, (float*)d_out);
}